// Round 7
// baseline (4139.796 us; speedup 1.0000x reference)
//
#include <hip/hip_runtime.h>
#include <hip/hip_bf16.h>

// ---------------------------------------------------------------------------
// 2-layer LSTM (B=256,S=512,E=128,H=256) + LayerNorm + projection.
// Round 7: fix round-6 scan xp-fragment stride bug (mt*2048 -> mt*256; the
// per-mt fragment is 256 u16 = 512B). Layout/logic otherwise identical to
// round 6: xp stored by xp_gemm in scan-fragment layout
//   e = ((t*16+bgrp)*8+ws)*2048 + mts*256 + (hi*16+lo)*4 + rs
// so each scan wave-load is one contiguous 512B transaction.
// Scan: persistent Whh (46 frags/lane VGPR + 18 frags/lane LDS), h double-
// buffer, 1 barrier/step, cvt_pk_bf16_f32 h packing, state persisted once.
// ws layout unchanged from round 2 (chunked over S, T from ws_size).
// ---------------------------------------------------------------------------

typedef unsigned short u16;
typedef unsigned int   u32;
using short8 = __attribute__((ext_vector_type(8))) short;
using f32x4  = __attribute__((ext_vector_type(4))) float;

#define NB 256
#define NS 512
#define NE 128
#define NH 256
#define NG 1024  // 4*H

// scan LDS: weights 8 waves * 18 frags * 64 lanes * 16B = 147456, then h dbuf
#define WLDS_FRAGS 18
#define HOFF 147456
#define SCAN_LDS (HOFF + 2 * 16 * NH * 2)   // 163840 = 160 KiB (CU max)

__device__ __forceinline__ u16 f2b(float x) {
  __hip_bfloat16 h = __float2bfloat16(x);
  return __builtin_bit_cast(u16, h);
}
__device__ __forceinline__ float b2f(u16 u) {
  return __builtin_bit_cast(float, (u32)u << 16);
}
__device__ __forceinline__ float sigf(float x) { return 1.0f / (1.0f + __expf(-x)); }
__device__ __forceinline__ float tanhfast(float x) {
  float e = __expf(2.0f * x);
  return 1.0f - 2.0f / (e + 1.0f);
}

// ---------------- prep: fp32 weights -> bf16, combined biases -------------
__global__ __launch_bounds__(256) void prep_weights(
    const float* Wih0, const float* Whh0, const float* bih0, const float* bhh0,
    const float* Wih1, const float* Whh1, const float* bih1, const float* bhh1,
    u16* wih0b, u16* whh0b, u16* wih1b, u16* whh1b, float* bc0, float* bc1) {
  int stride = gridDim.x * blockDim.x;
  int tid = blockIdx.x * blockDim.x + threadIdx.x;
  for (int i = tid; i < NG * NE; i += stride) wih0b[i] = f2b(Wih0[i]);
  for (int i = tid; i < NG * NH; i += stride) {
    whh0b[i] = f2b(Whh0[i]);
    wih1b[i] = f2b(Wih1[i]);
    whh1b[i] = f2b(Whh1[i]);
  }
  for (int i = tid; i < NG; i += stride) {
    bc0[i] = bih0[i] + bhh0[i];
    bc1[i] = bih1[i] + bhh1[i];
  }
}

// ---------------- embedding gather for steps [t0, t0+T) -------------------
__global__ __launch_bounds__(256) void embed_chunk(const int* __restrict__ x,
                                                   const float* __restrict__ emb,
                                                   u16* __restrict__ ebuf, int t0) {
  int gid = blockIdx.x * 256 + threadIdx.x;
  int d4 = gid & 31;
  int sb = gid >> 5;                            // sl*B + b
  int b  = sb & (NB - 1);
  int sl = sb >> 8;
  int tok = x[b * NS + (t0 + sl)];              // x is [B][S]
  float4 v = make_float4(0.f, 0.f, 0.f, 0.f);
  if (tok != 0) v = *(const float4*)(emb + (size_t)tok * NE + d4 * 4);
  ushort4 o;
  o.x = f2b(v.x); o.y = f2b(v.y); o.z = f2b(v.z); o.w = f2b(v.w);
  *(ushort4*)(ebuf + (size_t)sb * NE + d4 * 4) = o;
}

// ---------------- xp GEMM: writes scan-fragment layout ---------------------
// A: [T*256][K] bf16 row-major, W: [1024][K] bf16, out element for (row,gc):
//   t = row>>8, ba = row&255, bgrp=ba>>4, lo=ba&15
//   ws=(gc>>4)&7, mts=gc>>7, his=(gc>>2)&3, rs=gc&3
//   e = (((t*16+bgrp)*8+ws)*8+mts)*256 + (his*16+lo)*4 + rs
// => scan wave-load (one mt) = 64 lanes x 8B contiguous (512B).
template <int K>
__global__ __launch_bounds__(256) void xp_gemm(const u16* __restrict__ A,
                                               const u16* __restrict__ W,
                                               const float* __restrict__ bias,
                                               u16* __restrict__ Cout) {
  __shared__ __align__(16) char lds[2 * 128 * 80];
  char* Asm = lds;
  char* Bsm = lds + 128 * 80;
  int tid = threadIdx.x;
  int w = tid >> 6, l = tid & 63;
  int hi = l >> 4, lo = l & 15;
  int mblk = blockIdx.x >> 3, nblk = blockIdx.x & 7;
  size_t arow0 = (size_t)mblk * 128;
  int g0 = nblk * 128;
  int wm = (w >> 1) * 64, wn = (w & 1) * 64;
  f32x4 acc[4][4] = {};
  int r = tid >> 1, cp = tid & 1;

  for (int k0 = 0; k0 < K; k0 += 32) {
    int4 a0 = *(const int4*)(A + (arow0 + r) * K + k0 + cp * 16);
    int4 a1 = *(const int4*)(A + (arow0 + r) * K + k0 + cp * 16 + 8);
    int4 b0 = *(const int4*)(W + (size_t)(g0 + r) * K + k0 + cp * 16);
    int4 b1 = *(const int4*)(W + (size_t)(g0 + r) * K + k0 + cp * 16 + 8);
    *(int4*)(Asm + r * 80 + cp * 32)      = a0;
    *(int4*)(Asm + r * 80 + cp * 32 + 16) = a1;
    *(int4*)(Bsm + r * 80 + cp * 32)      = b0;
    *(int4*)(Bsm + r * 80 + cp * 32 + 16) = b1;
    __syncthreads();
    short8 af[4], bfr[4];
#pragma unroll
    for (int mt = 0; mt < 4; ++mt)
      af[mt] = *(const short8*)(Asm + (wm + mt * 16 + lo) * 80 + hi * 16);
#pragma unroll
    for (int nt = 0; nt < 4; ++nt)
      bfr[nt] = *(const short8*)(Bsm + (wn + nt * 16 + lo) * 80 + hi * 16);
#pragma unroll
    for (int mt = 0; mt < 4; ++mt)
#pragma unroll
      for (int nt = 0; nt < 4; ++nt)
        acc[mt][nt] = __builtin_amdgcn_mfma_f32_16x16x32_bf16(af[mt], bfr[nt], acc[mt][nt], 0, 0, 0);
    __syncthreads();
  }
  // epilogue: D lane mapping col = lane&15 (gc), row = (lane>>4)*4 + reg
#pragma unroll
  for (int nt = 0; nt < 4; ++nt) {
    int gc = g0 + wn + nt * 16 + lo;
    float bv = bias[gc];
    int ws_ = (gc >> 4) & 7, mts = gc >> 7, his = (gc >> 2) & 3, rs = gc & 3;
    size_t gbase = ((size_t)(ws_ * 8 + mts) << 8) + (size_t)(his * 16) * 4 + rs;
#pragma unroll
    for (int mt = 0; mt < 4; ++mt) {
      size_t row = arow0 + wm + mt * 16 + hi * 4;
#pragma unroll
      for (int rr = 0; rr < 4; ++rr) {
        size_t rw = row + rr;
        int t = (int)(rw >> 8), ba = (int)(rw & 255);
        size_t e = ((size_t)(t * 16 + (ba >> 4)) << 14) + gbase + (size_t)(ba & 15) * 4;
        Cout[e] = f2b(acc[mt][nt][rr] + bv);
      }
    }
  }
}

// ---------------- LSTM scan: persistent weights, h double-buffer -----------
// 16 WGs x 512 thr (8 waves), __launch_bounds__(512,2) -> 256 VGPR cap.
// Wave w owns gate rows 16*(w+8*mt)+lane, mt=0..7 (mt pairs = gate type).
// Whh frags (mt,p): p<2 all mt + p==2 mt<2 in LDS (18 slots), rest in VGPR.
// h LDS layout (frag-major, per buffer): element (b,k), k=32p+8h'+kap at
//   buf + p*1024 + sig(h'*16+b)*16 + kap*2,  sig(x)=x^((x>>3)&7)  (R4-verified)
// Double buffer: step t reads buf[t&1], writes buf[(t+1)&1] => ONE barrier.
// xp fragment layout: per (t, wave): 8 x 512B contiguous loads (mt*256 elems).
template <bool STORE_H>
__global__ __launch_bounds__(512, 2) void lstm_scan(const u16* __restrict__ xp,
                                                    const u16* __restrict__ whh,
                                                    u16* __restrict__ h_out,
                                                    float* __restrict__ h_state,
                                                    float* __restrict__ c_state,
                                                    int T, int first) {
  extern __shared__ __align__(16) char smem[];
  int tid = threadIdx.x;
  int w = tid >> 6, l = tid & 63;
  int hi = l >> 4, lo = l & 15;
  int bg = blockIdx.x * 16;

  // ---- load Whh into VGPRs + LDS (once) ----
  int wbase = w * (WLDS_FRAGS * 1024) + l * 16;   // per-lane 16B slots
  short8 wfv[8][5];   // p = 3..7
  short8 wfv2[6];     // p == 2, mt = 2..7
#pragma unroll
  for (int mt = 0; mt < 8; ++mt) {
#pragma unroll
    for (int p = 0; p < 8; ++p) {
      const u16* src = whh + (size_t)(16 * (w + 8 * mt) + lo) * NH + p * 32 + hi * 8;
      short8 v = *(const short8*)src;
      if (p < 2)                 *(short8*)(smem + wbase + (p * 8 + mt) * 1024) = v;
      else if (p == 2 && mt < 2) *(short8*)(smem + wbase + (16 + mt) * 1024) = v;
      else if (p == 2)           wfv2[mt - 2] = v;
      else                       wfv[mt][p - 3] = v;
    }
  }

  // ---- init h (LDS buffer 0, frag-major) and c (regs) ----
  float c[2][4];
  if (first) {
    for (int i = tid; i < 16 * NH / 2; i += 512) ((u32*)(smem + HOFF))[i] = 0;
#pragma unroll
    for (int g = 0; g < 2; ++g)
#pragma unroll
      for (int r = 0; r < 4; ++r) c[g][r] = 0.0f;
  } else {
    for (int i = tid; i < 16 * NH; i += 512) {
      int b = i >> 8, k = i & 255;
      int p = k >> 5, hp = (k >> 3) & 3, kp = k & 7;
      int xx = hp * 16 + b;
      u16 hb = f2b(h_state[(size_t)(bg + b) * NH + k]);
      *(u16*)(smem + HOFF + p * 1024 + (xx ^ ((xx >> 3) & 7)) * 16 + kp * 2) = hb;
    }
#pragma unroll
    for (int g = 0; g < 2; ++g)
#pragma unroll
      for (int r = 0; r < 4; ++r) {
        int j = 16 * w + 128 * g + hi * 4 + r;
        c[g][r] = c_state[(size_t)(bg + lo) * NH + j];
      }
  }
  __syncthreads();

  // ---- step-invariant offsets (relative to h buffer base) ----
  int rdoff = (l ^ ((l >> 3) & 7)) * 16;            // bfrag read offset
  int wroff[2];                                      // h write offsets (g=0,1)
#pragma unroll
  for (int g = 0; g < 2; ++g) {
    int xx = (2 * (w & 1) + (hi >> 1)) * 16 + lo;   // h'_j*16 + b
    wroff[g] = (4 * g + (w >> 1)) * 1024 + (xx ^ ((xx >> 3) & 7)) * 16 + 8 * (hi & 1);
  }
  // STORE_H writeback: thread -> (batch bq, k-chunk kc): logical chunk kc
  int bq = tid >> 5, kc = tid & 31;
  int xw = (kc & 3) * 16 + bq;
  int wboff = (kc >> 2) * 1024 + (xw ^ ((xw >> 3) & 7)) * 16;
  size_t wb_glob = (size_t)(bg + bq) * NH + kc * 8;

  // xp fragment-layout pointer: wave slice, per-lane 4 elements (8B)
  const u16* xpp = xp + ((size_t)(blockIdx.x * 8 + w) * 2048) + (size_t)l * 4;

  // ---- prefetch xp for t=0 ----
  ushort4 xq[8];
#pragma unroll
  for (int mt = 0; mt < 8; ++mt) xq[mt] = *(const ushort4*)(xpp + mt * 256);

  f32x4 acc[8];
  for (int t = 0; t < T; ++t) {
    int rbase = HOFF + ((t & 1) << 13);       // read buffer (h_{t-1})
    int wbbase = HOFF + ((~t & 1) << 13);     // write buffer (h_t)
    // acc init from prefetched xp (bias folded in by GEMM)
#pragma unroll
    for (int mt = 0; mt < 8; ++mt) {
      f32x4 a;
      a[0] = b2f(xq[mt].x); a[1] = b2f(xq[mt].y);
      a[2] = b2f(xq[mt].z); a[3] = b2f(xq[mt].w);
      acc[mt] = a;
    }
    // prefetch next step's xp (t=T-1 reads into iobuf region: safe, discarded)
    xpp += 262144;
#pragma unroll
    for (int mt = 0; mt < 8; ++mt) xq[mt] = *(const ushort4*)(xpp + mt * 256);
    // GEMV: 8 k-slots x 8 m-tiles; bfrag at rbase + rdoff + p*1024
#pragma unroll
    for (int p = 0; p < 8; ++p) {
      short8 bf = *(const short8*)(smem + rbase + rdoff + p * 1024);
#pragma unroll
      for (int mt = 0; mt < 8; ++mt) {
        short8 af;
        if (p < 2)                 af = *(const short8*)(smem + wbase + (p * 8 + mt) * 1024);
        else if (p == 2 && mt < 2) af = *(const short8*)(smem + wbase + (16 + mt) * 1024);
        else if (p == 2)           af = wfv2[mt - 2];
        else                       af = wfv[mt][p - 3];
        acc[mt] = __builtin_amdgcn_mfma_f32_16x16x32_bf16(af, bf, acc[mt], 0, 0, 0);
      }
    }
    // cell update: lane owns gate rows j = 16w+128g+4hi+r, batch col bg+lo;
    // writes h_t into the OTHER buffer (no hazard, no barrier here)
#pragma unroll
    for (int g = 0; g < 2; ++g) {
      float hv[4];
#pragma unroll
      for (int r = 0; r < 4; ++r) {
        float iv = sigf(acc[g][r]);
        float fv = sigf(acc[2 + g][r]);
        float gv = tanhfast(acc[4 + g][r]);
        float ov = sigf(acc[6 + g][r]);
        float cc = fv * c[g][r] + iv * gv;
        c[g][r] = cc;
        hv[r] = ov * tanhfast(cc);
      }
      u32 d0, d1;
      asm("v_cvt_pk_bf16_f32 %0, %1, %2" : "=v"(d0) : "v"(hv[0]), "v"(hv[1]));
      asm("v_cvt_pk_bf16_f32 %0, %1, %2" : "=v"(d1) : "v"(hv[2]), "v"(hv[3]));
      uint2 hw; hw.x = d0; hw.y = d1;
      *(uint2*)(smem + wbbase + wroff[g]) = hw;   // ds_write_b64, conflict-free
    }
    __syncthreads();  // h_t visible; ONLY barrier in the step
    if (STORE_H) {
      int4 hv4 = *(const int4*)(smem + wbbase + wboff);     // logical chunk kc
      *(int4*)(h_out + wb_glob + ((size_t)t << 16)) = hv4;  // global chunk kc
    }
  }

  // ---- persist state (once; h from final LDS buffer = bf16-rounded) ----
  int fbuf = HOFF + ((T & 1) << 13);
#pragma unroll
  for (int g = 0; g < 2; ++g) {
    ushort4 hv4 = *(const ushort4*)(smem + fbuf + wroff[g]);
    int j = 16 * w + 128 * g + 4 * hi;
    u16 hb[4] = {hv4.x, hv4.y, hv4.z, hv4.w};
#pragma unroll
    for (int r = 0; r < 4; ++r) {
      h_state[(size_t)(bg + lo) * NH + j + r] = b2f(hb[r]);
      c_state[(size_t)(bg + lo) * NH + j + r] = c[g][r];
    }
  }
}

// ---------------- LayerNorm + projection -----------------------------------
__global__ __launch_bounds__(256) void ln_proj(const float* __restrict__ hn,
                                               const float* __restrict__ lng,
                                               const float* __restrict__ lnb,
                                               const float* __restrict__ pW,
                                               const float* __restrict__ pb,
                                               float* __restrict__ out) {
  __shared__ __align__(16) float nbuf[NH];
  __shared__ float red[8];
  int b = blockIdx.x, tid = threadIdx.x;
  float v = hn[(size_t)b * NH + tid];
  float s = v, s2 = v * v;
#pragma unroll
  for (int o = 32; o > 0; o >>= 1) {
    s  += __shfl_down(s, o);
    s2 += __shfl_down(s2, o);
  }
  if ((tid & 63) == 0) { red[tid >> 6] = s; red[4 + (tid >> 6)] = s2; }
  __syncthreads();
  if (tid == 0) {
    red[0] = red[0] + red[1] + red[2] + red[3];
    red[4] = red[4] + red[5] + red[6] + red[7];
  }
  __syncthreads();
  float mean = red[0] * (1.0f / NH);
  float var  = red[4] * (1.0f / NH) - mean * mean;
  float rs = rsqrtf(var + 1e-5f);
  nbuf[tid] = (v - mean) * rs * lng[tid] + lnb[tid];
  __syncthreads();
  if (tid < NE) {
    float a = pb[tid];
    const float* wr = pW + (size_t)tid * NH;
#pragma unroll 4
    for (int j = 0; j < NH; ++j) a = fmaf(nbuf[j], wr[j], a);
    out[(size_t)b * NE + tid] = a;
  }
}

// ---------------------------------------------------------------------------
extern "C" void kernel_launch(void* const* d_in, const int* in_sizes, int n_in,
                              void* d_out, int out_size, void* d_ws, size_t ws_size,
                              hipStream_t stream) {
  const int*   x     = (const int*)d_in[0];
  const float* emb   = (const float*)d_in[1];
  const float* Wih0  = (const float*)d_in[2];
  const float* Whh0  = (const float*)d_in[3];
  const float* bih0  = (const float*)d_in[4];
  const float* bhh0  = (const float*)d_in[5];
  const float* Wih1  = (const float*)d_in[6];
  const float* Whh1  = (const float*)d_in[7];
  const float* bih1  = (const float*)d_in[8];
  const float* bhh1  = (const float*)d_in[9];
  const float* ln_g  = (const float*)d_in[10];
  const float* ln_b  = (const float*)d_in[11];
  const float* projW = (const float*)d_in[12];
  const float* projb = (const float*)d_in[13];

  // raise dynamic-LDS cap for the scan kernels (host-side attr, capture-safe)
  hipFuncSetAttribute((const void*)lstm_scan<true>,
                      hipFuncAttributeMaxDynamicSharedMemorySize, SCAN_LDS);
  hipFuncSetAttribute((const void*)lstm_scan<false>,
                      hipFuncAttributeMaxDynamicSharedMemorySize, SCAN_LDS);

  // pick largest chunk T (divides 512) whose scratch fits ws_size
  const size_t FIXED = 2891776;  // weights + biases + state
  int T = 512;
  while (T > 4 && FIXED + (size_t)T * 655360 > ws_size) T >>= 1;

  char* ws = (char*)d_ws;
  u16*   xp_c  = (u16*)(ws);
  u16*   iobuf = (u16*)(ws + (size_t)T * 524288);   // e chunk / h1 chunk
  char*  wbase = ws + (size_t)T * 655360;
  u16*   wih0b = (u16*)(wbase);
  u16*   whh0b = (u16*)(wbase + 262144);
  u16*   wih1b = (u16*)(wbase + 786432);
  u16*   whh1b = (u16*)(wbase + 1310720);
  float* bc0   = (float*)(wbase + 1835008);
  float* bc1   = (float*)(wbase + 1839104);
  float* h0s   = (float*)(wbase + 1843200);
  float* c0s   = (float*)(wbase + 2105344);
  float* h1s   = (float*)(wbase + 2367488);
  float* c1s   = (float*)(wbase + 2629632);

  prep_weights<<<256, 256, 0, stream>>>(Wih0, Whh0, bih0, bhh0, Wih1, Whh1, bih1, bhh1,
                                        wih0b, whh0b, wih1b, whh1b, bc0, bc1);
  int nch = NS / T;
  for (int c = 0; c < nch; ++c) {
    int t0 = c * T;
    embed_chunk<<<T * 32, 256, 0, stream>>>(x, emb, iobuf, t0);
    xp_gemm<NE><<<T * 16, 256, 0, stream>>>(iobuf, wih0b, bc0, xp_c);
    lstm_scan<true><<<16, 512, SCAN_LDS, stream>>>(xp_c, whh0b, iobuf, h0s, c0s, T, c == 0);
    xp_gemm<NH><<<T * 16, 256, 0, stream>>>(iobuf, wih1b, bc1, xp_c);
    lstm_scan<false><<<16, 512, SCAN_LDS, stream>>>(xp_c, whh1b, nullptr, h1s, c1s, T, c == 0);
  }
  ln_proj<<<NB, 256, 0, stream>>>(h1s, ln_g, ln_b, projW, projb, (float*)d_out);
}

// Round 9
// 2325.610 us; speedup vs baseline: 1.7801x; 1.7801x over previous
//
#include <hip/hip_runtime.h>
#include <hip/hip_bf16.h>

// ---------------------------------------------------------------------------
// 2-layer LSTM (B=256,S=512,E=128,H=256) + LayerNorm + projection.
// Round 9: exp2-domain gates done SAFELY. Round 8 failed because inline-asm
// v_exp/v_rcp defeat the compiler's trans->VALU hazard handling (CDNA needs
// wait states between a transcendental write and a dependent VALU read; the
// hazard recognizer can't see inside INLINEASM). Same math via
// __builtin_amdgcn_exp2f / __builtin_amdgcn_rcpf instead. Attribute
// experiment dropped: VGPR_Count=128 is arch-VGPRs only; weights live in
// AGPRs (no spill) -- keep round-7's __launch_bounds__(512,2).
// prep_weights prescales rows: i,f,o by log2e; g by 2*log2e.
// Everything else identical to round 7 (passed).
// ---------------------------------------------------------------------------

typedef unsigned short u16;
typedef unsigned int   u32;
using short8 = __attribute__((ext_vector_type(8))) short;
using f32x4  = __attribute__((ext_vector_type(4))) float;

#define NB 256
#define NS 512
#define NE 128
#define NH 256
#define NG 1024  // 4*H

// scan LDS: weights 8 waves * 18 frags * 64 lanes * 16B = 147456, then h dbuf
#define WLDS_FRAGS 18
#define HOFF 147456
#define SCAN_LDS (HOFF + 2 * 16 * NH * 2)   // 163840 = 160 KiB (CU max)

#define L2E     1.4426950408889634f
#define TWO_L2E 2.8853900817779268f

__device__ __forceinline__ u16 f2b(float x) {
  __hip_bfloat16 h = __float2bfloat16(x);
  return __builtin_bit_cast(u16, h);
}
__device__ __forceinline__ float b2f(u16 u) {
  return __builtin_bit_cast(float, (u32)u << 16);
}
// hardware transcendentals via builtins (hazards handled by codegen)
__device__ __forceinline__ float ex2(float x)  { return __builtin_amdgcn_exp2f(x); }
__device__ __forceinline__ float ex2n(float x) { return __builtin_amdgcn_exp2f(-x); }
__device__ __forceinline__ float rcpa(float x) { return __builtin_amdgcn_rcpf(x); }

// ---------------- prep: fp32 weights -> bf16 (exp2-prescaled), biases ------
// rows [0,256) i, [256,512) f, [512,768) g, [768,1024) o.
// i,f,o rows scaled by log2e; g rows by 2*log2e (tanh via exp2 of 2x*log2e).
__global__ __launch_bounds__(256) void prep_weights(
    const float* Wih0, const float* Whh0, const float* bih0, const float* bhh0,
    const float* Wih1, const float* Whh1, const float* bih1, const float* bhh1,
    u16* wih0b, u16* whh0b, u16* wih1b, u16* whh1b, float* bc0, float* bc1) {
  int stride = gridDim.x * blockDim.x;
  int tid = blockIdx.x * blockDim.x + threadIdx.x;
  for (int i = tid; i < NG * NE; i += stride) {
    float s = (((i >> 7) >> 8) == 2) ? TWO_L2E : L2E;
    wih0b[i] = f2b(Wih0[i] * s);
  }
  for (int i = tid; i < NG * NH; i += stride) {
    float s = (((i >> 8) >> 8) == 2) ? TWO_L2E : L2E;
    whh0b[i] = f2b(Whh0[i] * s);
    wih1b[i] = f2b(Wih1[i] * s);
    whh1b[i] = f2b(Whh1[i] * s);
  }
  for (int i = tid; i < NG; i += stride) {
    float s = ((i >> 8) == 2) ? TWO_L2E : L2E;
    bc0[i] = (bih0[i] + bhh0[i]) * s;
    bc1[i] = (bih1[i] + bhh1[i]) * s;
  }
}

// ---------------- embedding gather for steps [t0, t0+T) -------------------
__global__ __launch_bounds__(256) void embed_chunk(const int* __restrict__ x,
                                                   const float* __restrict__ emb,
                                                   u16* __restrict__ ebuf, int t0) {
  int gid = blockIdx.x * 256 + threadIdx.x;
  int d4 = gid & 31;
  int sb = gid >> 5;                            // sl*B + b
  int b  = sb & (NB - 1);
  int sl = sb >> 8;
  int tok = x[b * NS + (t0 + sl)];              // x is [B][S]
  float4 v = make_float4(0.f, 0.f, 0.f, 0.f);
  if (tok != 0) v = *(const float4*)(emb + (size_t)tok * NE + d4 * 4);
  ushort4 o;
  o.x = f2b(v.x); o.y = f2b(v.y); o.z = f2b(v.z); o.w = f2b(v.w);
  *(ushort4*)(ebuf + (size_t)sb * NE + d4 * 4) = o;
}

// ---------------- xp GEMM: writes scan-fragment layout ---------------------
//   e = (((t*16+bgrp)*8+ws)*8+mts)*256 + (his*16+lo)*4 + rs
template <int K>
__global__ __launch_bounds__(256) void xp_gemm(const u16* __restrict__ A,
                                               const u16* __restrict__ W,
                                               const float* __restrict__ bias,
                                               u16* __restrict__ Cout) {
  __shared__ __align__(16) char lds[2 * 128 * 80];
  char* Asm = lds;
  char* Bsm = lds + 128 * 80;
  int tid = threadIdx.x;
  int w = tid >> 6, l = tid & 63;
  int hi = l >> 4, lo = l & 15;
  int mblk = blockIdx.x >> 3, nblk = blockIdx.x & 7;
  size_t arow0 = (size_t)mblk * 128;
  int g0 = nblk * 128;
  int wm = (w >> 1) * 64, wn = (w & 1) * 64;
  f32x4 acc[4][4] = {};
  int r = tid >> 1, cp = tid & 1;

  for (int k0 = 0; k0 < K; k0 += 32) {
    int4 a0 = *(const int4*)(A + (arow0 + r) * K + k0 + cp * 16);
    int4 a1 = *(const int4*)(A + (arow0 + r) * K + k0 + cp * 16 + 8);
    int4 b0 = *(const int4*)(W + (size_t)(g0 + r) * K + k0 + cp * 16);
    int4 b1 = *(const int4*)(W + (size_t)(g0 + r) * K + k0 + cp * 16 + 8);
    *(int4*)(Asm + r * 80 + cp * 32)      = a0;
    *(int4*)(Asm + r * 80 + cp * 32 + 16) = a1;
    *(int4*)(Bsm + r * 80 + cp * 32)      = b0;
    *(int4*)(Bsm + r * 80 + cp * 32 + 16) = b1;
    __syncthreads();
    short8 af[4], bfr[4];
#pragma unroll
    for (int mt = 0; mt < 4; ++mt)
      af[mt] = *(const short8*)(Asm + (wm + mt * 16 + lo) * 80 + hi * 16);
#pragma unroll
    for (int nt = 0; nt < 4; ++nt)
      bfr[nt] = *(const short8*)(Bsm + (wn + nt * 16 + lo) * 80 + hi * 16);
#pragma unroll
    for (int mt = 0; mt < 4; ++mt)
#pragma unroll
      for (int nt = 0; nt < 4; ++nt)
        acc[mt][nt] = __builtin_amdgcn_mfma_f32_16x16x32_bf16(af[mt], bfr[nt], acc[mt][nt], 0, 0, 0);
    __syncthreads();
  }
  // epilogue: D lane mapping col = lane&15 (gc), row = (lane>>4)*4 + reg
#pragma unroll
  for (int nt = 0; nt < 4; ++nt) {
    int gc = g0 + wn + nt * 16 + lo;
    float bv = bias[gc];
    int ws_ = (gc >> 4) & 7, mts = gc >> 7, his = (gc >> 2) & 3, rs = gc & 3;
    size_t gbase = ((size_t)(ws_ * 8 + mts) << 8) + (size_t)(his * 16) * 4 + rs;
#pragma unroll
    for (int mt = 0; mt < 4; ++mt) {
      size_t row = arow0 + wm + mt * 16 + hi * 4;
#pragma unroll
      for (int rr = 0; rr < 4; ++rr) {
        size_t rw = row + rr;
        int t = (int)(rw >> 8), ba = (int)(rw & 255);
        size_t e = ((size_t)(t * 16 + (ba >> 4)) << 14) + gbase + (size_t)(ba & 15) * 4;
        Cout[e] = f2b(acc[mt][nt][rr] + bv);
      }
    }
  }
}

// ---------------- LSTM scan: persistent weights, h double-buffer -----------
// 16 WGs x 512 thr (8 waves), __launch_bounds__(512,2).
// Wave w owns gate rows 16*(w+8*mt)+lane, mt=0..7 (mt pairs = gate type).
// Whh frags (mt,p): p<2 all mt + p==2 mt<2 in LDS (18 slots), rest in AGPRs.
// h LDS layout (frag-major, per buffer): element (b,k), k=32p+8h'+kap at
//   buf + p*1024 + sig(h'*16+b)*16 + kap*2,  sig(x)=x^((x>>3)&7)  (R4-verified)
// Double buffer: step t reads buf[t&1], writes buf[(t+1)&1] => ONE barrier.
// xp fragment layout: per (t, wave): 8 x 512B contiguous loads (mt*256 elems).
template <bool STORE_H>
__global__ __launch_bounds__(512, 2) void lstm_scan(const u16* __restrict__ xp,
                                                    const u16* __restrict__ whh,
                                                    u16* __restrict__ h_out,
                                                    float* __restrict__ h_state,
                                                    float* __restrict__ c_state,
                                                    int T, int first) {
  extern __shared__ __align__(16) char smem[];
  int tid = threadIdx.x;
  int w = tid >> 6, l = tid & 63;
  int hi = l >> 4, lo = l & 15;
  int bg = blockIdx.x * 16;

  // ---- load Whh into VGPRs/AGPRs + LDS (once) ----
  int wbase = w * (WLDS_FRAGS * 1024) + l * 16;   // per-lane 16B slots
  short8 wfv[8][5];   // p = 3..7
  short8 wfv2[6];     // p == 2, mt = 2..7
#pragma unroll
  for (int mt = 0; mt < 8; ++mt) {
#pragma unroll
    for (int p = 0; p < 8; ++p) {
      const u16* src = whh + (size_t)(16 * (w + 8 * mt) + lo) * NH + p * 32 + hi * 8;
      short8 v = *(const short8*)src;
      if (p < 2)                 *(short8*)(smem + wbase + (p * 8 + mt) * 1024) = v;
      else if (p == 2 && mt < 2) *(short8*)(smem + wbase + (16 + mt) * 1024) = v;
      else if (p == 2)           wfv2[mt - 2] = v;
      else                       wfv[mt][p - 3] = v;
    }
  }

  // ---- init h (LDS buffer 0, frag-major) and c (regs) ----
  float c[2][4];
  if (first) {
    for (int i = tid; i < 16 * NH / 2; i += 512) ((u32*)(smem + HOFF))[i] = 0;
#pragma unroll
    for (int g = 0; g < 2; ++g)
#pragma unroll
      for (int r = 0; r < 4; ++r) c[g][r] = 0.0f;
  } else {
    for (int i = tid; i < 16 * NH; i += 512) {
      int b = i >> 8, k = i & 255;
      int p = k >> 5, hp = (k >> 3) & 3, kp = k & 7;
      int xx = hp * 16 + b;
      u16 hb = f2b(h_state[(size_t)(bg + b) * NH + k]);
      *(u16*)(smem + HOFF + p * 1024 + (xx ^ ((xx >> 3) & 7)) * 16 + kp * 2) = hb;
    }
#pragma unroll
    for (int g = 0; g < 2; ++g)
#pragma unroll
      for (int r = 0; r < 4; ++r) {
        int j = 16 * w + 128 * g + hi * 4 + r;
        c[g][r] = c_state[(size_t)(bg + lo) * NH + j];
      }
  }
  __syncthreads();

  // ---- step-invariant offsets (relative to h buffer base) ----
  int rdoff = (l ^ ((l >> 3) & 7)) * 16;            // bfrag read offset
  int wroff[2];                                      // h write offsets (g=0,1)
#pragma unroll
  for (int g = 0; g < 2; ++g) {
    int xx = (2 * (w & 1) + (hi >> 1)) * 16 + lo;   // h'_j*16 + b
    wroff[g] = (4 * g + (w >> 1)) * 1024 + (xx ^ ((xx >> 3) & 7)) * 16 + 8 * (hi & 1);
  }
  // STORE_H writeback: thread -> (batch bq, k-chunk kc): logical chunk kc
  int bq = tid >> 5, kc = tid & 31;
  int xw = (kc & 3) * 16 + bq;
  int wboff = (kc >> 2) * 1024 + (xw ^ ((xw >> 3) & 7)) * 16;
  size_t wb_glob = (size_t)(bg + bq) * NH + kc * 8;

  // xp fragment-layout pointer: wave slice, per-lane 4 elements (8B)
  const u16* xpp = xp + ((size_t)(blockIdx.x * 8 + w) * 2048) + (size_t)l * 4;

  // ---- prefetch xp for t=0 ----
  ushort4 xq[8];
#pragma unroll
  for (int mt = 0; mt < 8; ++mt) xq[mt] = *(const ushort4*)(xpp + mt * 256);

  f32x4 acc[8];
  for (int t = 0; t < T; ++t) {
    int rbase = HOFF + ((t & 1) << 13);       // read buffer (h_{t-1})
    int wbbase = HOFF + ((~t & 1) << 13);     // write buffer (h_t)
    // acc init from prefetched xp (bias folded in by GEMM)
#pragma unroll
    for (int mt = 0; mt < 8; ++mt) {
      f32x4 a;
      a[0] = b2f(xq[mt].x); a[1] = b2f(xq[mt].y);
      a[2] = b2f(xq[mt].z); a[3] = b2f(xq[mt].w);
      acc[mt] = a;
    }
    // prefetch next step's xp (t=T-1 reads into iobuf region: safe, discarded)
    xpp += 262144;
#pragma unroll
    for (int mt = 0; mt < 8; ++mt) xq[mt] = *(const ushort4*)(xpp + mt * 256);
    // GEMV: 8 k-slots x 8 m-tiles; bfrag at rbase + rdoff + p*1024
#pragma unroll
    for (int p = 0; p < 8; ++p) {
      short8 bf = *(const short8*)(smem + rbase + rdoff + p * 1024);
#pragma unroll
      for (int mt = 0; mt < 8; ++mt) {
        short8 af;
        if (p < 2)                 af = *(const short8*)(smem + wbase + (p * 8 + mt) * 1024);
        else if (p == 2 && mt < 2) af = *(const short8*)(smem + wbase + (16 + mt) * 1024);
        else if (p == 2)           af = wfv2[mt - 2];
        else                       af = wfv[mt][p - 3];
        acc[mt] = __builtin_amdgcn_mfma_f32_16x16x32_bf16(af, bf, acc[mt], 0, 0, 0);
      }
    }
    // cell update (exp2 domain): lane owns gate rows j = 16w+128g+4hi+r
#pragma unroll
    for (int g = 0; g < 2; ++g) {
      float hv[4];
#pragma unroll
      for (int r = 0; r < 4; ++r) {
        float iv = rcpa(1.0f + ex2n(acc[g][r]));
        float fv = rcpa(1.0f + ex2n(acc[2 + g][r]));
        float gv = 1.0f - 2.0f * rcpa(ex2(acc[4 + g][r]) + 1.0f);
        float ov = rcpa(1.0f + ex2n(acc[6 + g][r]));
        float cc = fv * c[g][r] + iv * gv;
        c[g][r] = cc;
        float th = 1.0f - 2.0f * rcpa(ex2(cc * TWO_L2E) + 1.0f);
        hv[r] = ov * th;
      }
      u32 d0, d1;
      asm("v_cvt_pk_bf16_f32 %0, %1, %2" : "=v"(d0) : "v"(hv[0]), "v"(hv[1]));
      asm("v_cvt_pk_bf16_f32 %0, %1, %2" : "=v"(d1) : "v"(hv[2]), "v"(hv[3]));
      uint2 hw; hw.x = d0; hw.y = d1;
      *(uint2*)(smem + wbbase + wroff[g]) = hw;   // ds_write_b64, conflict-free
    }
    __syncthreads();  // h_t visible; ONLY barrier in the step
    if (STORE_H) {
      int4 hv4 = *(const int4*)(smem + wbbase + wboff);     // logical chunk kc
      *(int4*)(h_out + wb_glob + ((size_t)t << 16)) = hv4;  // global chunk kc
    }
  }

  // ---- persist state (once; h from final LDS buffer = bf16-rounded) ----
  int fbuf = HOFF + ((T & 1) << 13);
#pragma unroll
  for (int g = 0; g < 2; ++g) {
    ushort4 hv4 = *(const ushort4*)(smem + fbuf + wroff[g]);
    int j = 16 * w + 128 * g + 4 * hi;
    u16 hb[4] = {hv4.x, hv4.y, hv4.z, hv4.w};
#pragma unroll
    for (int r = 0; r < 4; ++r) {
      h_state[(size_t)(bg + lo) * NH + j + r] = b2f(hb[r]);
      c_state[(size_t)(bg + lo) * NH + j + r] = c[g][r];
    }
  }
}

// ---------------- LayerNorm + projection -----------------------------------
__global__ __launch_bounds__(256) void ln_proj(const float* __restrict__ hn,
                                               const float* __restrict__ lng,
                                               const float* __restrict__ lnb,
                                               const float* __restrict__ pW,
                                               const float* __restrict__ pb,
                                               float* __restrict__ out) {
  __shared__ __align__(16) float nbuf[NH];
  __shared__ float red[8];
  int b = blockIdx.x, tid = threadIdx.x;
  float v = hn[(size_t)b * NH + tid];
  float s = v, s2 = v * v;
#pragma unroll
  for (int o = 32; o > 0; o >>= 1) {
    s  += __shfl_down(s, o);
    s2 += __shfl_down(s2, o);
  }
  if ((tid & 63) == 0) { red[tid >> 6] = s; red[4 + (tid >> 6)] = s2; }
  __syncthreads();
  if (tid == 0) {
    red[0] = red[0] + red[1] + red[2] + red[3];
    red[4] = red[4] + red[5] + red[6] + red[7];
  }
  __syncthreads();
  float mean = red[0] * (1.0f / NH);
  float var  = red[4] * (1.0f / NH) - mean * mean;
  float rs = rsqrtf(var + 1e-5f);
  nbuf[tid] = (v - mean) * rs * lng[tid] + lnb[tid];
  __syncthreads();
  if (tid < NE) {
    float a = pb[tid];
    const float* wr = pW + (size_t)tid * NH;
#pragma unroll 4
    for (int j = 0; j < NH; ++j) a = fmaf(nbuf[j], wr[j], a);
    out[(size_t)b * NE + tid] = a;
  }
}

// ---------------------------------------------------------------------------
extern "C" void kernel_launch(void* const* d_in, const int* in_sizes, int n_in,
                              void* d_out, int out_size, void* d_ws, size_t ws_size,
                              hipStream_t stream) {
  const int*   x     = (const int*)d_in[0];
  const float* emb   = (const float*)d_in[1];
  const float* Wih0  = (const float*)d_in[2];
  const float* Whh0  = (const float*)d_in[3];
  const float* bih0  = (const float*)d_in[4];
  const float* bhh0  = (const float*)d_in[5];
  const float* Wih1  = (const float*)d_in[6];
  const float* Whh1  = (const float*)d_in[7];
  const float* bih1  = (const float*)d_in[8];
  const float* bhh1  = (const float*)d_in[9];
  const float* ln_g  = (const float*)d_in[10];
  const float* ln_b  = (const float*)d_in[11];
  const float* projW = (const float*)d_in[12];
  const float* projb = (const float*)d_in[13];

  // raise dynamic-LDS cap for the scan kernels (host-side attr, capture-safe)
  hipFuncSetAttribute((const void*)lstm_scan<true>,
                      hipFuncAttributeMaxDynamicSharedMemorySize, SCAN_LDS);
  hipFuncSetAttribute((const void*)lstm_scan<false>,
                      hipFuncAttributeMaxDynamicSharedMemorySize, SCAN_LDS);

  // pick largest chunk T (divides 512) whose scratch fits ws_size
  const size_t FIXED = 2891776;  // weights + biases + state
  int T = 512;
  while (T > 4 && FIXED + (size_t)T * 655360 > ws_size) T >>= 1;

  char* ws = (char*)d_ws;
  u16*   xp_c  = (u16*)(ws);
  u16*   iobuf = (u16*)(ws + (size_t)T * 524288);   // e chunk / h1 chunk
  char*  wbase = ws + (size_t)T * 655360;
  u16*   wih0b = (u16*)(wbase);
  u16*   whh0b = (u16*)(wbase + 262144);
  u16*   wih1b = (u16*)(wbase + 786432);
  u16*   whh1b = (u16*)(wbase + 1310720);
  float* bc0   = (float*)(wbase + 1835008);
  float* bc1   = (float*)(wbase + 1839104);
  float* h0s   = (float*)(wbase + 1843200);
  float* c0s   = (float*)(wbase + 2105344);
  float* h1s   = (float*)(wbase + 2367488);
  float* c1s   = (float*)(wbase + 2629632);

  prep_weights<<<256, 256, 0, stream>>>(Wih0, Whh0, bih0, bhh0, Wih1, Whh1, bih1, bhh1,
                                        wih0b, whh0b, wih1b, whh1b, bc0, bc1);
  int nch = NS / T;
  for (int c = 0; c < nch; ++c) {
    int t0 = c * T;
    embed_chunk<<<T * 32, 256, 0, stream>>>(x, emb, iobuf, t0);
    xp_gemm<NE><<<T * 16, 256, 0, stream>>>(iobuf, wih0b, bc0, xp_c);
    lstm_scan<true><<<16, 512, SCAN_LDS, stream>>>(xp_c, whh0b, iobuf, h0s, c0s, T, c == 0);
    xp_gemm<NH><<<T * 16, 256, 0, stream>>>(iobuf, wih1b, bc1, xp_c);
    lstm_scan<false><<<16, 512, SCAN_LDS, stream>>>(xp_c, whh1b, nullptr, h1s, c1s, T, c == 0);
  }
  ln_proj<<<NB, 256, 0, stream>>>(h1s, ln_g, ln_b, projW, projb, (float*)d_out);
}